// Round 1
// baseline (296.865 us; speedup 1.0000x reference)
//
#include <hip/hip_runtime.h>
#include <hip/hip_bf16.h>
#include <stdint.h>

#define NROWS 32768
#define MCOLS 8192
#define DDIM  256

#define BM 128
#define BN 128
#define BK 64

typedef __attribute__((ext_vector_type(8))) short short8_t;
typedef __attribute__((ext_vector_type(4))) float f32x4;

__device__ __forceinline__ unsigned short f2bf(float f) {
  uint32_t u = __float_as_uint(f);
  u += 0x7FFFu + ((u >> 16) & 1u);   // round-to-nearest-even
  return (unsigned short)(u >> 16);
}

// order-preserving float -> uint key (for integer atomicMin == float min)
__device__ __forceinline__ uint32_t fkey(float f) {
  uint32_t b = __float_as_uint(f);
  return (b & 0x80000000u) ? ~b : (b | 0x80000000u);
}
__device__ __forceinline__ float funkey(uint32_t k) {
  uint32_t b = (k & 0x80000000u) ? (k ^ 0x80000000u) : ~k;
  return __uint_as_float(b);
}

// ---- K1: convert X,Y to bf16; init rowkey to +inf key; zero sum accumulator
__global__ void k_prep(const float* __restrict__ X, const float* __restrict__ Y,
                       unsigned short* __restrict__ Xb, unsigned short* __restrict__ Yb,
                       uint32_t* __restrict__ rowkey, float* __restrict__ sum_accum)
{
  const int tid = blockIdx.x * blockDim.x + threadIdx.x;
  const int stride = gridDim.x * blockDim.x;
  const int nx4 = NROWS * DDIM / 4;
  const int ny4 = MCOLS * DDIM / 4;
  for (int i = tid; i < nx4; i += stride) {
    float4 v = ((const float4*)X)[i];
    ushort4 o;
    o.x = f2bf(v.x); o.y = f2bf(v.y); o.z = f2bf(v.z); o.w = f2bf(v.w);
    ((ushort4*)Xb)[i] = o;
  }
  for (int i = tid; i < ny4; i += stride) {
    float4 v = ((const float4*)Y)[i];
    ushort4 o;
    o.x = f2bf(v.x); o.y = f2bf(v.y); o.z = f2bf(v.z); o.w = f2bf(v.w);
    ((ushort4*)Yb)[i] = o;
  }
  for (int i = tid; i < NROWS; i += stride) rowkey[i] = 0xFFFFFFFFu;
  if (tid == 0) sum_accum[0] = 0.0f;
}

// ---- K2: c[j] = 0.5*||y_j||^2 - psi[j]   (exact fp32, wave per row)
__global__ void k_prepc(const float* __restrict__ Y, const float* __restrict__ psi,
                        float* __restrict__ cbuf)
{
  const int lane = threadIdx.x & 63;
  const int gw = (blockIdx.x * blockDim.x + threadIdx.x) >> 6;
  const int nw = (gridDim.x * blockDim.x) >> 6;
  for (int row = gw; row < MCOLS; row += nw) {
    float4 v = ((const float4*)(Y + (size_t)row * DDIM))[lane];
    float s = v.x*v.x + v.y*v.y + v.z*v.z + v.w*v.w;
    #pragma unroll
    for (int m = 32; m >= 1; m >>= 1) s += __shfl_xor(s, m);
    if (lane == 0) cbuf[row] = 0.5f * s - psi[row];
  }
}

// ---- K3: fused MFMA GEMM (cross = Xb * Yb^T) + per-row min of (c[j] - dot)
__global__ __launch_bounds__(256) void k_gemm(
    const unsigned short* __restrict__ Xb, const unsigned short* __restrict__ Yb,
    const float* __restrict__ cbuf, uint32_t* __restrict__ rowkey)
{
  __shared__ __align__(16) unsigned short As[BM * BK];
  __shared__ __align__(16) unsigned short Bs[BN * BK];

  // bijective XCD swizzle (nwg % 8 == 0), col-fastest tile order:
  // each XCD sweeps all 64 col-strips for a contiguous band of row-tiles,
  // keeping the current A tile and the Y strips L2-resident.
  const int nwg = gridDim.x;
  const int cpx = nwg >> 3;
  const int swz = (blockIdx.x & 7) * cpx + (blockIdx.x >> 3);
  const int tile_col = swz & (MCOLS / BN - 1);
  const int tile_row = swz / (MCOLS / BN);
  const int brow = tile_row * BM;
  const int bcol = tile_col * BN;

  const int tid = threadIdx.x;
  const int wid = tid >> 6;
  const int lane = tid & 63;
  const int wr = wid >> 1;   // wave row 0..1  (64-row half)
  const int wc = wid & 1;    // wave col 0..1  (64-col half)

  f32x4 acc[4][4] = {};

  // staging: each wave stages 32 rows of A and 32 rows of B per K-step,
  // 4 x global_load_lds(16B) each; LDS layout is linear [row][BK].
  const int srow = wid * 32 + (lane >> 3);
  const int scol = (lane & 7) * 8;
  const unsigned short* aSrc = Xb + (size_t)(brow + srow) * DDIM + scol;
  const unsigned short* bSrc = Yb + (size_t)(bcol + srow) * DDIM + scol;

  const unsigned short* aFrag = As + ((wr * 64) + (lane & 15)) * BK + ((lane >> 4) * 8);
  const unsigned short* bFrag = Bs + ((wc * 64) + (lane & 15)) * BK + ((lane >> 4) * 8);

  for (int k0 = 0; k0 < DDIM; k0 += BK) {
    #pragma unroll
    for (int i = 0; i < 4; i++) {
      __builtin_amdgcn_global_load_lds(
          (const __attribute__((address_space(1))) uint32_t*)(aSrc + i * 8 * DDIM + k0),
          (__attribute__((address_space(3))) uint32_t*)(As + (wid * 32 + i * 8) * BK),
          16, 0, 0);
      __builtin_amdgcn_global_load_lds(
          (const __attribute__((address_space(1))) uint32_t*)(bSrc + i * 8 * DDIM + k0),
          (__attribute__((address_space(3))) uint32_t*)(Bs + (wid * 32 + i * 8) * BK),
          16, 0, 0);
    }
    __syncthreads();
    #pragma unroll
    for (int kk = 0; kk < 2; kk++) {
      short8_t a[4], b[4];
      #pragma unroll
      for (int m = 0; m < 4; m++)
        a[m] = *(const short8_t*)(aFrag + m * 16 * BK + kk * 32);
      #pragma unroll
      for (int n = 0; n < 4; n++)
        b[n] = *(const short8_t*)(bFrag + n * 16 * BK + kk * 32);
      #pragma unroll
      for (int m = 0; m < 4; m++)
        #pragma unroll
        for (int n = 0; n < 4; n++)
          acc[m][n] = __builtin_amdgcn_mfma_f32_16x16x32_bf16(a[m], b[n], acc[m][n], 0, 0, 0);
    }
    __syncthreads();
  }

  // epilogue: v = min_n (c[col] - dot); C/D layout: col = lane&15, row = (lane>>4)*4 + reg
  float vmin[4][4];
  #pragma unroll
  for (int m = 0; m < 4; m++)
    #pragma unroll
    for (int r = 0; r < 4; r++)
      vmin[m][r] = 3.4e38f;

  #pragma unroll
  for (int n = 0; n < 4; n++) {
    const int col = bcol + wc * 64 + n * 16 + (lane & 15);
    const float cj = cbuf[col];
    #pragma unroll
    for (int m = 0; m < 4; m++)
      #pragma unroll
      for (int r = 0; r < 4; r++)
        vmin[m][r] = fminf(vmin[m][r], cj - acc[m][n][r]);
  }
  // min across the 16 columns held by lanes sharing (lane>>4)
  #pragma unroll
  for (int m = 0; m < 4; m++)
    #pragma unroll
    for (int r = 0; r < 4; r++) {
      float v = vmin[m][r];
      v = fminf(v, __shfl_xor(v, 1));
      v = fminf(v, __shfl_xor(v, 2));
      v = fminf(v, __shfl_xor(v, 4));
      v = fminf(v, __shfl_xor(v, 8));
      vmin[m][r] = v;
    }
  if ((lane & 15) < 4) {
    const int r = lane & 15;
    const int g = lane >> 4;
    #pragma unroll
    for (int m = 0; m < 4; m++) {
      const int row = brow + wr * 64 + m * 16 + g * 4 + r;
      atomicMin((unsigned int*)&rowkey[row], fkey(vmin[m][r]));
    }
  }
}

// ---- K4: row_min[i] = decoded_min + 0.5*||x_i||^2 (exact fp32); sum into accumulator
__global__ void k_rowred(const float* __restrict__ X, const uint32_t* __restrict__ rowkey,
                         float* __restrict__ sum_accum)
{
  const int lane = threadIdx.x & 63;
  const int gw = (blockIdx.x * blockDim.x + threadIdx.x) >> 6;
  const int nw = (gridDim.x * blockDim.x) >> 6;
  float acc = 0.f;
  for (int row = gw; row < NROWS; row += nw) {
    float4 v = ((const float4*)(X + (size_t)row * DDIM))[lane];
    float s = v.x*v.x + v.y*v.y + v.z*v.z + v.w*v.w;
    #pragma unroll
    for (int m = 32; m >= 1; m >>= 1) s += __shfl_xor(s, m);
    acc += funkey(rowkey[row]) + 0.5f * s;   // identical on all lanes
  }
  if (lane == 0) atomicAdd(sum_accum, acc);
}

// ---- K5: out = sum/N + mean(psi)
__global__ void k_final(const float* __restrict__ psi, const float* __restrict__ sum_accum,
                        float* __restrict__ out)
{
  __shared__ float sh[4];
  float s = 0.f;
  for (int i = threadIdx.x; i < MCOLS; i += 256) s += psi[i];
  #pragma unroll
  for (int m = 32; m >= 1; m >>= 1) s += __shfl_xor(s, m);
  const int wid = threadIdx.x >> 6, lane = threadIdx.x & 63;
  if (lane == 0) sh[wid] = s;
  __syncthreads();
  if (threadIdx.x == 0)
    out[0] = sum_accum[0] / (float)NROWS + (sh[0] + sh[1] + sh[2] + sh[3]) / (float)MCOLS;
}

extern "C" void kernel_launch(void* const* d_in, const int* in_sizes, int n_in,
                              void* d_out, int out_size, void* d_ws, size_t ws_size,
                              hipStream_t stream)
{
  const float* X   = (const float*)d_in[0];
  const float* Y   = (const float*)d_in[1];
  const float* psi = (const float*)d_in[2];
  float* out = (float*)d_out;

  // workspace layout (~21.2 MB total)
  char* ws = (char*)d_ws;
  unsigned short* Xb = (unsigned short*)(ws);                                   // 16,777,216 B
  unsigned short* Yb = (unsigned short*)(ws + (size_t)NROWS * DDIM * 2);        //  4,194,304 B
  float* cbuf        = (float*)(ws + (size_t)(NROWS + MCOLS) * DDIM * 2);       //     32,768 B
  uint32_t* rowkey   = (uint32_t*)((char*)cbuf + (size_t)MCOLS * 4);            //    131,072 B
  float* sum_accum   = (float*)((char*)rowkey + (size_t)NROWS * 4);             //          4 B

  k_prep <<<2048, 256, 0, stream>>>(X, Y, Xb, Yb, rowkey, sum_accum);
  k_prepc<<<512,  256, 0, stream>>>(Y, psi, cbuf);
  k_gemm <<<(NROWS / BM) * (MCOLS / BN), 256, 0, stream>>>(Xb, Yb, cbuf, rowkey);
  k_rowred<<<1024, 256, 0, stream>>>(X, rowkey, sum_accum);
  k_final<<<1, 256, 0, stream>>>(psi, sum_accum, out);
}

// Round 2
// 252.269 us; speedup vs baseline: 1.1768x; 1.1768x over previous
//
#include <hip/hip_runtime.h>
#include <hip/hip_bf16.h>
#include <stdint.h>

#define NROWS 32768
#define MCOLS 8192
#define DDIM  256

#define BM 256
#define BN 256
#define BK 64
#define NWG ((NROWS/BM)*(MCOLS/BN))   // 128 * 32 = 4096

typedef __attribute__((ext_vector_type(8))) short short8_t;
typedef __attribute__((ext_vector_type(4))) float f32x4;

__device__ __forceinline__ unsigned short f2bf(float f) {
  uint32_t u = __float_as_uint(f);
  u += 0x7FFFu + ((u >> 16) & 1u);   // round-to-nearest-even
  return (unsigned short)(u >> 16);
}

// order-preserving float -> uint key (integer atomicMin == float min)
__device__ __forceinline__ uint32_t fkey(float f) {
  uint32_t b = __float_as_uint(f);
  return (b & 0x80000000u) ? ~b : (b | 0x80000000u);
}
__device__ __forceinline__ float funkey(uint32_t k) {
  uint32_t b = (k & 0x80000000u) ? (k ^ 0x80000000u) : ~k;
  return __uint_as_float(b);
}

// ---- K1: fused prep: bf16 convert X,Y; xhalf = 0.5||x||^2; cbuf = 0.5||y||^2 - psi;
//          init rowkey, zero accumulator.
__global__ void k_prep(const float* __restrict__ X, const float* __restrict__ Y,
                       const float* __restrict__ psi,
                       unsigned short* __restrict__ Xb, unsigned short* __restrict__ Yb,
                       float* __restrict__ xhalf, float* __restrict__ cbuf,
                       uint32_t* __restrict__ rowkey, float* __restrict__ sum_accum)
{
  const int lane = threadIdx.x & 63;
  const int gw = (blockIdx.x * blockDim.x + threadIdx.x) >> 6;
  const int nw = (gridDim.x * blockDim.x) >> 6;
  for (int row = gw; row < NROWS + MCOLS; row += nw) {
    const bool isX = row < NROWS;
    const int r = isX ? row : row - NROWS;
    const float* src = isX ? (X + (size_t)row * DDIM) : (Y + (size_t)r * DDIM);
    float4 v = ((const float4*)src)[lane];
    ushort4 o;
    o.x = f2bf(v.x); o.y = f2bf(v.y); o.z = f2bf(v.z); o.w = f2bf(v.w);
    if (isX) ((ushort4*)(Xb + (size_t)row * DDIM))[lane] = o;
    else     ((ushort4*)(Yb + (size_t)r   * DDIM))[lane] = o;
    float s = v.x*v.x + v.y*v.y + v.z*v.z + v.w*v.w;
    #pragma unroll
    for (int m = 32; m >= 1; m >>= 1) s += __shfl_xor(s, m);
    if (lane == 0) {
      if (isX) { xhalf[row] = 0.5f * s; rowkey[row] = 0xFFFFFFFFu; }
      else     { cbuf[r] = 0.5f * s - psi[r]; }
    }
  }
  if (blockIdx.x == 0 && threadIdx.x == 0) sum_accum[0] = 0.0f;
}

// ---- stage one 64-row round (8 KiB) of a K-tile chunk into LDS.
// LDS dest is linear (wave-uniform base + lane*16); the T2 swizzle is applied by
// pre-swizzling the GLOBAL source column (same involution as the read side).
#define STAGE64(gmat, gbase, ltile, row0, kbyte) do {                          \
    const int _row = (row0) + wid * 8 + (lane >> 3);                           \
    const char* _g = (const char*)(gmat) + (size_t)((gbase) + _row) * 512      \
                     + (kbyte) + (((lane & 7) ^ (lane >> 3)) << 4);            \
    __builtin_amdgcn_global_load_lds(                                          \
        (const __attribute__((address_space(1))) uint32_t*)_g,                 \
        (__attribute__((address_space(3))) uint32_t*)                          \
            ((char*)(ltile) + ((row0) + wid * 8) * 128), 16, 0, 0);            \
  } while (0)

#define LOAD_A(mh, kk, buf) do {                                               \
    const char* _p = aBase + (buf) * 32768 + (mh) * 8192;                      \
    const int _co = (kk) ? coff1 : coff0;                                      \
    av[0] = *(const short8_t*)(_p +    0 + _co);                               \
    av[1] = *(const short8_t*)(_p + 2048 + _co);                               \
    av[2] = *(const short8_t*)(_p + 4096 + _co);                               \
    av[3] = *(const short8_t*)(_p + 6144 + _co);                               \
  } while (0)

#define LOAD_B(kk, buf) do {                                                   \
    const char* _p = bBase + (buf) * 32768;                                    \
    const int _co = (kk) ? coff1 : coff0;                                      \
    bfr[kk][0] = *(const short8_t*)(_p +    0 + _co);                          \
    bfr[kk][1] = *(const short8_t*)(_p + 2048 + _co);                          \
    bfr[kk][2] = *(const short8_t*)(_p + 4096 + _co);                          \
    bfr[kk][3] = *(const short8_t*)(_p + 6144 + _co);                          \
  } while (0)

#define MFMA16(mh, kk) do {                                                    \
    __builtin_amdgcn_s_setprio(1);                                             \
    _Pragma("unroll") for (int _m = 0; _m < 4; ++_m)                           \
    _Pragma("unroll") for (int _n = 0; _n < 4; ++_n)                           \
      acc[(mh)*4+_m][_n] = __builtin_amdgcn_mfma_f32_16x16x32_bf16(            \
          av[_m], bfr[kk][_n], acc[(mh)*4+_m][_n], 0, 0, 0);                   \
    __builtin_amdgcn_s_setprio(0);                                             \
  } while (0)

// ---- K2: 256x256 8-phase MFMA GEMM + fused per-row min of (c[j] - dot)
__global__ __launch_bounds__(512, 2) void k_gemm(
    const unsigned short* __restrict__ Xb, const unsigned short* __restrict__ Yb,
    const float* __restrict__ cbuf, uint32_t* __restrict__ rowkey)
{
  __shared__ __align__(16) unsigned short As[2][BM * BK];
  __shared__ __align__(16) unsigned short Bs[2][BN * BK];

  // bijective XCD swizzle (NWG % 8 == 0), col-fastest: each XCD sweeps all 32
  // col strips for 16 contiguous row tiles (B stays L2-resident).
  const int bid = blockIdx.x;
  const int swz = (bid & 7) * (NWG / 8) + (bid >> 3);
  const int brow = (swz >> 5) * BM;
  const int bcol = (swz & 31) * BN;

  const int tid  = threadIdx.x;
  const int wid  = tid >> 6;     // 0..7
  const int lane = tid & 63;
  const int wr = wid >> 2;       // 0..1 -> rows wr*128
  const int wc = wid & 3;        // 0..3 -> cols wc*64

  // read-side swizzled column offsets (bytes) for kk=0/1
  const int coff0 = ((((lane >> 4))     ^ (lane & 7)) << 4);
  const int coff1 = (((4 | (lane >> 4)) ^ (lane & 7)) << 4);

  const char* aBase = (const char*)&As[0][0] + (wr * 128 + (lane & 15)) * 128;
  const char* bBase = (const char*)&Bs[0][0] + (wc * 64  + (lane & 15)) * 128;

  f32x4 acc[8][4] = {};
  short8_t av[4];
  short8_t bfr[2][4];

  // prologue: stage tile0 (buf0): B rows 0..255, A mh0 rows, A mh1 rows last
  STAGE64(Yb, bcol, &Bs[0][0],   0, 0);
  STAGE64(Yb, bcol, &Bs[0][0],  64, 0);
  STAGE64(Yb, bcol, &Bs[0][0], 128, 0);
  STAGE64(Yb, bcol, &Bs[0][0], 192, 0);
  STAGE64(Xb, brow, &As[0][0],   0, 0);
  STAGE64(Xb, brow, &As[0][0], 128, 0);
  STAGE64(Xb, brow, &As[0][0],  64, 0);
  STAGE64(Xb, brow, &As[0][0], 192, 0);
  asm volatile("s_waitcnt vmcnt(2)" ::: "memory");   // B + A-mh0 landed; A-mh1 may fly
  __builtin_amdgcn_s_barrier();

  #pragma unroll
  for (int t = 0; t < 4; ++t) {
    const int buf  = t & 1;
    const int nbuf = buf ^ 1;
    const int kbn  = (t + 1) * 128;   // next tile's K byte offset

    // ---- phase 0: mh0, kk0  (stage next B rows 0-127)
    LOAD_A(0, 0, buf);
    LOAD_B(0, buf);
    if (t < 3) { STAGE64(Yb, bcol, &Bs[nbuf][0],  0, kbn);
                 STAGE64(Yb, bcol, &Bs[nbuf][0], 64, kbn); }
    __builtin_amdgcn_s_barrier();
    MFMA16(0, 0);
    __builtin_amdgcn_s_barrier();

    // ---- phase 1: mh0, kk1  (stage next B rows 128-255)
    LOAD_A(0, 1, buf);
    LOAD_B(1, buf);
    if (t < 3) { STAGE64(Yb, bcol, &Bs[nbuf][0], 128, kbn);
                 STAGE64(Yb, bcol, &Bs[nbuf][0], 192, kbn); }
    __builtin_amdgcn_s_barrier();
    MFMA16(0, 1);
    if (t < 3) asm volatile("s_waitcnt vmcnt(4)" ::: "memory"); // cur A-mh1 in; next B flying
    else       asm volatile("s_waitcnt vmcnt(0)" ::: "memory");
    __builtin_amdgcn_s_barrier();

    // ---- phase 2: mh1, kk0  (stage next A mh0 rows)
    LOAD_A(1, 0, buf);
    if (t < 3) { STAGE64(Xb, brow, &As[nbuf][0],   0, kbn);
                 STAGE64(Xb, brow, &As[nbuf][0], 128, kbn); }
    __builtin_amdgcn_s_barrier();
    MFMA16(1, 0);
    __builtin_amdgcn_s_barrier();

    // ---- phase 3: mh1, kk1  (stage next A mh1 rows)
    LOAD_A(1, 1, buf);
    if (t < 3) { STAGE64(Xb, brow, &As[nbuf][0],  64, kbn);
                 STAGE64(Xb, brow, &As[nbuf][0], 192, kbn); }
    __builtin_amdgcn_s_barrier();
    MFMA16(1, 1);
    if (t < 3) asm volatile("s_waitcnt vmcnt(2)" ::: "memory"); // next B + A-mh0 in; A-mh1 may fly
    __builtin_amdgcn_s_barrier();
  }

  // ---- epilogue: per-row min of (c[col] - dot), then atomicMin on encoded keys.
  // C/D layout: col = lane&15, row = (lane>>4)*4 + reg
  float cj[4];
  #pragma unroll
  for (int n = 0; n < 4; ++n)
    cj[n] = cbuf[bcol + wc * 64 + n * 16 + (lane & 15)];

  const int rsel = lane & 15;
  #pragma unroll
  for (int m = 0; m < 8; ++m) {
    float vr0, vr1, vr2, vr3;
    {
      float v = cj[0] - acc[m][0][0];
      v = fminf(v, cj[1] - acc[m][1][0]);
      v = fminf(v, cj[2] - acc[m][2][0]);
      v = fminf(v, cj[3] - acc[m][3][0]);
      #pragma unroll
      for (int s = 1; s <= 8; s <<= 1) v = fminf(v, __shfl_xor(v, s));
      vr0 = v;
    }
    {
      float v = cj[0] - acc[m][0][1];
      v = fminf(v, cj[1] - acc[m][1][1]);
      v = fminf(v, cj[2] - acc[m][2][1]);
      v = fminf(v, cj[3] - acc[m][3][1]);
      #pragma unroll
      for (int s = 1; s <= 8; s <<= 1) v = fminf(v, __shfl_xor(v, s));
      vr1 = v;
    }
    {
      float v = cj[0] - acc[m][0][2];
      v = fminf(v, cj[1] - acc[m][1][2]);
      v = fminf(v, cj[2] - acc[m][2][2]);
      v = fminf(v, cj[3] - acc[m][3][2]);
      #pragma unroll
      for (int s = 1; s <= 8; s <<= 1) v = fminf(v, __shfl_xor(v, s));
      vr2 = v;
    }
    {
      float v = cj[0] - acc[m][0][3];
      v = fminf(v, cj[1] - acc[m][1][3]);
      v = fminf(v, cj[2] - acc[m][2][3]);
      v = fminf(v, cj[3] - acc[m][3][3]);
      #pragma unroll
      for (int s = 1; s <= 8; s <<= 1) v = fminf(v, __shfl_xor(v, s));
      vr3 = v;
    }
    if (rsel < 4) {
      float vsel = vr0;
      vsel = (rsel == 1) ? vr1 : vsel;
      vsel = (rsel == 2) ? vr2 : vsel;
      vsel = (rsel == 3) ? vr3 : vsel;
      const int row = brow + wr * 128 + m * 16 + (lane >> 4) * 4 + rsel;
      atomicMin((unsigned int*)&rowkey[row], fkey(vsel));
    }
  }
}

// ---- K3: sum over rows of (min + 0.5||x||^2)
__global__ void k_rowred(const float* __restrict__ xhalf, const uint32_t* __restrict__ rowkey,
                         float* __restrict__ sum_accum)
{
  __shared__ float sh[4];
  const int i = blockIdx.x * 256 + threadIdx.x;
  float v = funkey(rowkey[i]) + xhalf[i];
  #pragma unroll
  for (int m = 32; m >= 1; m >>= 1) v += __shfl_xor(v, m);
  const int wid = threadIdx.x >> 6, lane = threadIdx.x & 63;
  if (lane == 0) sh[wid] = v;
  __syncthreads();
  if (threadIdx.x == 0) atomicAdd(sum_accum, sh[0] + sh[1] + sh[2] + sh[3]);
}

// ---- K4: out = sum/N + mean(psi)
__global__ void k_final(const float* __restrict__ psi, const float* __restrict__ sum_accum,
                        float* __restrict__ out)
{
  __shared__ float sh[4];
  float s = 0.f;
  for (int i = threadIdx.x; i < MCOLS; i += 256) s += psi[i];
  #pragma unroll
  for (int m = 32; m >= 1; m >>= 1) s += __shfl_xor(s, m);
  const int wid = threadIdx.x >> 6, lane = threadIdx.x & 63;
  if (lane == 0) sh[wid] = s;
  __syncthreads();
  if (threadIdx.x == 0)
    out[0] = sum_accum[0] / (float)NROWS + (sh[0] + sh[1] + sh[2] + sh[3]) / (float)MCOLS;
}

extern "C" void kernel_launch(void* const* d_in, const int* in_sizes, int n_in,
                              void* d_out, int out_size, void* d_ws, size_t ws_size,
                              hipStream_t stream)
{
  const float* X   = (const float*)d_in[0];
  const float* Y   = (const float*)d_in[1];
  const float* psi = (const float*)d_in[2];
  float* out = (float*)d_out;

  char* ws = (char*)d_ws;
  unsigned short* Xb = (unsigned short*)(ws);                                   // 16,777,216 B
  unsigned short* Yb = (unsigned short*)(ws + (size_t)NROWS * DDIM * 2);        //  4,194,304 B
  float* cbuf        = (float*)(ws + (size_t)(NROWS + MCOLS) * DDIM * 2);       //     32,768 B
  uint32_t* rowkey   = (uint32_t*)((char*)cbuf + (size_t)MCOLS * 4);            //    131,072 B
  float* xhalf       = (float*)((char*)rowkey + (size_t)NROWS * 4);             //    131,072 B
  float* sum_accum   = (float*)((char*)xhalf + (size_t)NROWS * 4);              //          4 B

  k_prep  <<<2048, 256, 0, stream>>>(X, Y, psi, Xb, Yb, xhalf, cbuf, rowkey, sum_accum);
  k_gemm  <<<NWG, 512, 0, stream>>>(Xb, Yb, cbuf, rowkey);
  k_rowred<<<NROWS / 256, 256, 0, stream>>>(xhalf, rowkey, sum_accum);
  k_final <<<1, 256, 0, stream>>>(psi, sum_accum, out);
}